// Round 17
// baseline (150.382 us; speedup 1.0000x reference)
//
#include <hip/hip_runtime.h>
#include <cstdint>
#include <cstddef>

#define S 8192
#define Dm 1024
#define E 64
#define CAP 128
#define SEC 67108864ull   // S*E*CAP
// out layout (float32 elements), out_size = 1 + 2*SEC + 64 = 134,217,793:
//   [0] l_aux | [1,1+SEC) combine | [1+SEC,1+2SEC) dispatch | [1+2SEC,+64) counts
// Coverage map (every element written every call):
//   k_fillscan fill blocks: elements [4, 134217728) = 0
//   k_fillscan scan blk0:   elements 1,2,3 and 134217728 (=out[2SEC]) = 0
//   k_fillscan scan blk e:  counts out[1+2SEC+e]
//   k_scatter:              sparse combine/dispatch overwrites; out[0] = l_aux

#define GEMM_BLOCKS 256   // 32 tokens x 64 experts, 512 thr (8 waves: latency)
#define SCAN_BLOCKS 64
#define FILL_BLOCKS 1984  // 64+1984 = 2048
#define N4F 33554432u     // fill chunk bound: elements [4, 134217728)
#define WSCALE 4096.0f    // keep w_hi/w_lo out of fp16-denorm range
#define INV_WSCALE (1.0f / 4096.0f)

typedef float f32x4 __attribute__((ext_vector_type(4)));
typedef _Float16 f16x4 __attribute__((ext_vector_type(4)));
typedef _Float16 f16x8 __attribute__((ext_vector_type(8)));

// 4 fp32 -> f16 hi + lo (8B stores)
#define CV4(H, L, ROW, COL, V, SCALE) do {                                     \
    f16x4 hh, ll; float t_;                                                    \
    t_ = (V).x * (SCALE); hh[0] = (_Float16)t_; ll[0] = (_Float16)(t_ - (float)hh[0]); \
    t_ = (V).y * (SCALE); hh[1] = (_Float16)t_; ll[1] = (_Float16)(t_ - (float)hh[1]); \
    t_ = (V).z * (SCALE); hh[2] = (_Float16)t_; ll[2] = (_Float16)(t_ - (float)hh[2]); \
    t_ = (V).w * (SCALE); hh[3] = (_Float16)t_; ll[3] = (_Float16)(t_ - (float)hh[3]); \
    *(f16x4*)&H[ROW][COL] = hh;                                                \
    *(f16x4*)&L[ROW][COL] = ll;                                                \
} while (0)

// ---------------- K1: standalone MFMA GEMM + softmax/argmax ------------------
// R16-verified fp16x3 MFMA math (x·w = hi·hi + lo·hi + hi·lo, W pre-scaled by
// 4096), now STANDALONE at full read BW (R16 showed the fused version is
// wedged at the read/write-interference wall regardless of compute). 256
// blocks x 512 threads = 8 waves/CU on all 256 CUs; wave wv owns (m-tile
// wv&1, n-tile wv>>1); 2-deep p/q register prefetch.
__global__ __launch_bounds__(512) void k_gemm(const float* __restrict__ x,
                                              const float* __restrict__ w,
                                              float* __restrict__ gate,
                                              int* __restrict__ idx,
                                              float* __restrict__ me_part) {
    int bid = blockIdx.x;
    int tid = threadIdx.x;
    __shared__ _Float16 Ah[32][72];    // 144B rows: 16B-aligned
    __shared__ _Float16 Alo[32][72];
    __shared__ _Float16 Wh[64][72];
    __shared__ _Float16 Wlo[64][72];
    __shared__ float Sl[32][66];
    __shared__ float sm[32];
    __shared__ float sinv[32];
    int t0 = bid * 32;
    // staging maps: A = 32x64 (1 float4/thread), W = 64x64 (2 float4/thread)
    int ar = tid >> 4;                 // 0..31
    int ac = (tid & 15) * 4;
    int wr = tid >> 3;                 // 0..63
    int wc = (tid & 7) * 8;
    const float* asrc = x + (size_t)(t0 + ar) * Dm + ac;
    const float* wsrc = w + (size_t)wr * Dm + wc;

    // MFMA split: wave wv -> (mt = wv&1, nt = wv>>1)
    int wv = tid >> 6;
    int l = tid & 63;
    int lr = l & 15;
    int lg = l >> 4;
    int mt = wv & 1;
    int nt = wv >> 1;
    f32x4 acc = {0.f, 0.f, 0.f, 0.f};

    // 2-deep prefetch: p = even chunks, q = odd
    float4 pa = *(const float4*)(asrc + 0);
    float4 pw0 = *(const float4*)(wsrc + 0);
    float4 pw1 = *(const float4*)(wsrc + 4);
    float4 qa = *(const float4*)(asrc + 64);
    float4 qw0 = *(const float4*)(wsrc + 64);
    float4 qw1 = *(const float4*)(wsrc + 68);

#define WRITE_LDS(A, W0, W1)                                                   \
    CV4(Ah, Alo, ar, ac, A, 1.0f);                                             \
    CV4(Wh, Wlo, wr, wc, W0, WSCALE);                                          \
    CV4(Wh, Wlo, wr, (wc + 4), W1, WSCALE);

#define LOADP(KB)                                                              \
    pa = *(const float4*)(asrc + (KB));                                        \
    pw0 = *(const float4*)(wsrc + (KB));                                       \
    pw1 = *(const float4*)(wsrc + (KB) + 4);

#define LOADQ(KB)                                                              \
    qa = *(const float4*)(asrc + (KB));                                        \
    qw0 = *(const float4*)(wsrc + (KB));                                       \
    qw1 = *(const float4*)(wsrc + (KB) + 4);

#define INNER_MFMA                                                             \
    _Pragma("unroll")                                                          \
    for (int ks = 0; ks < 2; ++ks) {                                           \
        int kc = ks * 32 + lg * 8;                                             \
        f16x8 ah = *(const f16x8*)&Ah[mt * 16 + lr][kc];                       \
        f16x8 al = *(const f16x8*)&Alo[mt * 16 + lr][kc];                      \
        f16x8 bh = *(const f16x8*)&Wh[nt * 16 + lr][kc];                       \
        f16x8 bl = *(const f16x8*)&Wlo[nt * 16 + lr][kc];                      \
        acc = __builtin_amdgcn_mfma_f32_16x16x32_f16(ah, bh, acc, 0, 0, 0);    \
        acc = __builtin_amdgcn_mfma_f32_16x16x32_f16(al, bh, acc, 0, 0, 0);    \
        acc = __builtin_amdgcn_mfma_f32_16x16x32_f16(ah, bl, acc, 0, 0, 0);    \
    }

    for (int ch = 0; ch < 16; ch += 2) {
        // even chunk: write p -> LDS, refill p (ch+2), compute
        __syncthreads();
        WRITE_LDS(pa, pw0, pw1)
        __syncthreads();
        if (ch + 2 < 16) { LOADP((ch + 2) * 64) }
        INNER_MFMA
        // odd chunk: write q -> LDS, refill q (ch+3), compute
        __syncthreads();
        WRITE_LDS(qa, qw0, qw1)
        __syncthreads();
        if (ch + 3 < 16) { LOADQ((ch + 3) * 64) }
        INNER_MFMA
    }
#undef WRITE_LDS
#undef LOADP
#undef LOADQ
#undef INNER_MFMA
    __syncthreads();
    // D -> Sl (R16-verified C/D layout: row = lg*4 + r, col = lr)
#pragma unroll
    for (int r = 0; r < 4; ++r)
        Sl[mt * 16 + lg * 4 + r][nt * 16 + lr] = acc[r] * INV_WSCALE;
    __syncthreads();
    if (tid < 32) {   // row phase: first-index argmax + exp-sum
        float m = Sl[tid][0];
        int am = 0;
#pragma unroll
        for (int c = 1; c < E; ++c) {
            float v = Sl[tid][c];
            if (v > m) { m = v; am = c; }
        }
        float ssum = 0.f;
#pragma unroll
        for (int c = 0; c < E; ++c) ssum += __expf(Sl[tid][c] - m);
        float inv = 1.0f / ssum;   // softmax value at the argmax
        gate[t0 + tid] = inv;
        idx[t0 + tid] = am;
        sm[tid] = m;
        sinv[tid] = inv;
    }
    __syncthreads();
    if (tid < E) {    // column phase: partial me sums (deterministic)
        float cs = 0.f;
#pragma unroll 8
        for (int r = 0; r < 32; ++r)
            cs += __expf(Sl[r][tid] - sm[r]) * sinv[r];
        me_part[bid * E + tid] = cs;
    }
}

// ---------------- K2: 537MB zero-fill with the expert scan hidden inside -----
// R11's passed kernel, verbatim. Scan blocks [0,64) write tg/la_part/counts
// and boundary zeros; fill blocks [64,2048) zero elements [4, 134217728).
__global__ __launch_bounds__(256) void k_fillscan(const int* __restrict__ idx,
                                                  const float* __restrict__ gate,
                                                  const float* __restrict__ me_part,
                                                  float2* __restrict__ tg,
                                                  float* __restrict__ la_part,
                                                  float* __restrict__ out) {
    int bid = blockIdx.x;
    int tid = threadIdx.x;
    if (bid < SCAN_BLOCKS) {
        __shared__ int wsum[4];
        __shared__ float red[256];
        int e = bid;
        int lane = tid & 63;
        int wid = tid >> 6;
        if (bid == 0 && tid == 0) {   // boundary elements not covered by fill
            out[1] = 0.f; out[2] = 0.f; out[3] = 0.f;
            out[2 * SEC] = 0.f;
        }
        int running = 0;
        for (int ch = 0; ch < S / 256; ++ch) {
            int t = ch * 256 + tid;
            bool f = (idx[t] == e);
            unsigned long long b = __ballot(f);
            int pre = __popcll(b & ((1ull << lane) - 1ull));
            if (lane == 0) wsum[wid] = __popcll(b);
            __syncthreads();
            int off = running;
#pragma unroll
            for (int w2 = 0; w2 < 4; ++w2)
                if (w2 < wid) off += wsum[w2];
            int p = off + pre;
            if (f) {   // every token written by exactly its argmax expert
                int tgt = (p < CAP) ? e * CAP + p : -1;
                tg[t] = make_float2(__int_as_float(tgt), gate[t]);
            }
            running += wsum[0] + wsum[1] + wsum[2] + wsum[3];
            __syncthreads();
        }
        // me reduction over 256 GEMM blocks
        red[tid] = me_part[tid * E + e];
        __syncthreads();
        for (int s2 = 128; s2 > 0; s2 >>= 1) {
            if (tid < s2) red[tid] += red[tid + s2];
            __syncthreads();
        }
        if (tid == 0) {
            out[1 + 2 * SEC + e] = (float)running;   // exp_counts (pre-drop)
            la_part[e] = red[0] * (1.0f / (float)S) *
                         ((float)running / (float)S) * (float)E;
        }
    } else {
        int fb = bid - SCAN_BLOCKS;
        f32x4 z = {0.f, 0.f, 0.f, 0.f};
        f32x4* o4 = (f32x4*)out;
        for (unsigned i = 1u + (unsigned)fb * 256u + tid; i < N4F;
             i += FILL_BLOCKS * 256u)
            o4[i] = z;
    }
}

// ---------------- K3: sparse scatter + l_aux ----------------
// R11's passed kernel, verbatim.
__global__ __launch_bounds__(256) void k_scatter(const float2* __restrict__ tg,
                                                 const float* __restrict__ la_part,
                                                 float* __restrict__ out) {
    int bid = blockIdx.x;
    int tid = threadIdx.x;
    if (bid == 32) {
        if (tid < E) {
            float la = la_part[tid];
#pragma unroll
            for (int off = 32; off > 0; off >>= 1)
                la += __shfl_down(la, off, 64);
            if (tid == 0) out[0] = la;
        }
        return;
    }
    int t = bid * 256 + tid;
    float2 g = tg[t];
    int tgt = __float_as_int(g.x);
    if (tgt >= 0) {
        size_t o = 1 + (size_t)t * (E * CAP) + (size_t)tgt;
        out[o] = g.y;                 // combine_weights
        out[o + SEC] = 1.0f;          // dispatch_mask
    }
}

extern "C" void kernel_launch(void* const* d_in, const int* in_sizes, int n_in,
                              void* d_out, int out_size, void* d_ws, size_t ws_size,
                              hipStream_t stream) {
    const float* x = (const float*)d_in[0];      // [S, Dm] fp32
    const float* w = (const float*)d_in[1];      // [E, Dm] fp32
    float* out = (float*)d_out;

    // ws layout
    float* me_part = (float*)d_ws;               // [256][64] = 64 KB
    float* gate = me_part + GEMM_BLOCKS * E;     // S floats
    int* idx = (int*)(gate + S);                 // S ints
    float2* tg = (float2*)(idx + S);             // S float2 = 64 KB
    float* la_part = (float*)(tg + S);           // 64 floats

    k_gemm<<<dim3(GEMM_BLOCKS), dim3(512), 0, stream>>>(x, w, gate, idx, me_part);
    k_fillscan<<<dim3(SCAN_BLOCKS + FILL_BLOCKS), dim3(256), 0, stream>>>(
        idx, gate, me_part, tg, la_part, out);
    k_scatter<<<dim3(33), dim3(256), 0, stream>>>(tg, la_part, out);
}

// Round 18
// 143.716 us; speedup vs baseline: 1.0464x; 1.0464x over previous
//
#include <hip/hip_runtime.h>
#include <cstdint>
#include <cstddef>

#define S 8192
#define Dm 1024
#define E 64
#define CAP 128
#define SEC 67108864ull   // S*E*CAP
// out layout (float32 elements), out_size = 1 + 2*SEC + 64 = 134,217,793:
//   [0] l_aux | [1,1+SEC) combine | [1+SEC,1+2SEC) dispatch | [1+2SEC,+64) counts
// K1 fill zeroes elements [0,134217792) (incl. out[0]; k_scan atomicAdds l_aux
// into it); leftover element = counts[63] written unconditionally by k_scan.

#define GEMM_BLOCKS 64    // 128 tokens x 64 experts each (W refetch: 16 MB)
#define FILL_BLOCKS 960   // grid 1024 x 512 thr
#define NTHR 512
#define N4ALL 33554448u
#define WSCALE 4096.0f    // keep w_hi/w_lo out of fp16-denorm range
#define INV_WSCALE (1.0f / 4096.0f)

typedef float f32x4 __attribute__((ext_vector_type(4)));
typedef _Float16 f16x4 __attribute__((ext_vector_type(4)));
typedef _Float16 f16x8 __attribute__((ext_vector_type(8)));

// 4 fp32 -> f16 hi + lo (8B stores)
#define CV4(H, L, ROW, COL, V, SCALE) do {                                     \
    f16x4 hh, ll; float t_;                                                    \
    t_ = (V).x * (SCALE); hh[0] = (_Float16)t_; ll[0] = (_Float16)(t_ - (float)hh[0]); \
    t_ = (V).y * (SCALE); hh[1] = (_Float16)t_; ll[1] = (_Float16)(t_ - (float)hh[1]); \
    t_ = (V).z * (SCALE); hh[2] = (_Float16)t_; ll[2] = (_Float16)(t_ - (float)hh[2]); \
    t_ = (V).w * (SCALE); hh[3] = (_Float16)t_; ll[3] = (_Float16)(t_ - (float)hh[3]); \
    *(f16x4*)&H[ROW][COL] = hh;                                                \
    *(f16x4*)&L[ROW][COL] = ll;                                                \
} while (0)

// ---------------- K1: fused {128-tok MFMA GEMM+softmax} + 537MB zero-fill ----
// R16-verified fp16x3 MFMA math; ONE structural change vs champion: 128-token
// tiles (64 blocks), cutting GEMM read traffic 96->48 MB. Theory (R17):
// the fused GEMM overhead (~46us) is read traffic interleaved against the
// write-saturated HBM stream (turnaround cost ~3x), additive with the fill —
// so halving reads should cut k_main ~15-23us. MFMA keeps the big tile cheap
// (acc = 4 f32x4/wave; no R6-style VALU/VGPR blowup).
__global__ __launch_bounds__(512) void k_main(const float* __restrict__ x,
                                              const float* __restrict__ w,
                                              float* __restrict__ gate,
                                              int* __restrict__ idx,
                                              float* __restrict__ me_part,
                                              float* __restrict__ out) {
    int bid = blockIdx.x;
    int tid = threadIdx.x;
    if (bid < GEMM_BLOCKS) {
        // LDS carve: Ah/Alo/Wh/Wlo for the loop; Sl aliases Ah/Alo after it.
        __shared__ __align__(16) char smem[56320];
        _Float16 (*Ah)[72]  = (_Float16(*)[72])(smem);            // 18432 B
        _Float16 (*Alo)[72] = (_Float16(*)[72])(smem + 18432);    // 18432 B
        _Float16 (*Wh)[72]  = (_Float16(*)[72])(smem + 36864);    //  9216 B
        _Float16 (*Wlo)[72] = (_Float16(*)[72])(smem + 46080);    //  9216 B
        float (*Sl)[66] = (float(*)[66])(smem);                   // 33792 B alias
        float* sm = (float*)(smem + 55296);                       // 128 f32
        float* sinv = (float*)(smem + 55808);                     // 128 f32
        int t0 = bid * 128;
        // staging maps: A 128x64 (4 float4/thread), W 64x64 (2 float4/thread)
        int ar = tid >> 4;                 // 0..31 (rows ar, ar+32, +64, +96)
        int ac = (tid & 15) * 4;
        int wr = tid >> 3;                 // 0..63
        int wc = (tid & 7) * 8;
        const float* asrc = x + (size_t)(t0 + ar) * Dm + ac;
        const float* wsrc = w + (size_t)wr * Dm + wc;

        // MFMA split: wave wv = m-strip (16 tokens); each wave does 4 n-tiles
        int wv = tid >> 6;
        int l = tid & 63;
        int lr = l & 15;
        int lg = l >> 4;
        f32x4 acc0 = {0.f, 0.f, 0.f, 0.f};
        f32x4 acc1 = {0.f, 0.f, 0.f, 0.f};
        f32x4 acc2 = {0.f, 0.f, 0.f, 0.f};
        f32x4 acc3 = {0.f, 0.f, 0.f, 0.f};

        // 2-deep prefetch: p = even chunks, q = odd
        float4 pa0, pa1, pa2, pa3, pw0, pw1;
        float4 qa0, qa1, qa2, qa3, qw0, qw1;
#define LOADP(KB)                                                              \
        pa0 = *(const float4*)(asrc + (KB));                                   \
        pa1 = *(const float4*)(asrc + 32 * Dm + (KB));                         \
        pa2 = *(const float4*)(asrc + 64 * Dm + (KB));                         \
        pa3 = *(const float4*)(asrc + 96 * Dm + (KB));                         \
        pw0 = *(const float4*)(wsrc + (KB));                                   \
        pw1 = *(const float4*)(wsrc + (KB) + 4);
#define LOADQ(KB)                                                              \
        qa0 = *(const float4*)(asrc + (KB));                                   \
        qa1 = *(const float4*)(asrc + 32 * Dm + (KB));                         \
        qa2 = *(const float4*)(asrc + 64 * Dm + (KB));                         \
        qa3 = *(const float4*)(asrc + 96 * Dm + (KB));                         \
        qw0 = *(const float4*)(wsrc + (KB));                                   \
        qw1 = *(const float4*)(wsrc + (KB) + 4);
#define WRITE_LDS(A0, A1, A2, A3, W0, W1)                                      \
        CV4(Ah, Alo, ar, ac, A0, 1.0f);                                        \
        CV4(Ah, Alo, (ar + 32), ac, A1, 1.0f);                                 \
        CV4(Ah, Alo, (ar + 64), ac, A2, 1.0f);                                 \
        CV4(Ah, Alo, (ar + 96), ac, A3, 1.0f);                                 \
        CV4(Wh, Wlo, wr, wc, W0, WSCALE);                                      \
        CV4(Wh, Wlo, wr, (wc + 4), W1, WSCALE);
#define INNER_MFMA                                                             \
        _Pragma("unroll")                                                      \
        for (int ks = 0; ks < 2; ++ks) {                                       \
            int kc = ks * 32 + lg * 8;                                         \
            f16x8 ah = *(const f16x8*)&Ah[wv * 16 + lr][kc];                   \
            f16x8 al = *(const f16x8*)&Alo[wv * 16 + lr][kc];                  \
            f16x8 bh0 = *(const f16x8*)&Wh[lr][kc];                            \
            f16x8 bl0 = *(const f16x8*)&Wlo[lr][kc];                           \
            f16x8 bh1 = *(const f16x8*)&Wh[16 + lr][kc];                       \
            f16x8 bl1 = *(const f16x8*)&Wlo[16 + lr][kc];                      \
            f16x8 bh2 = *(const f16x8*)&Wh[32 + lr][kc];                       \
            f16x8 bl2 = *(const f16x8*)&Wlo[32 + lr][kc];                      \
            f16x8 bh3 = *(const f16x8*)&Wh[48 + lr][kc];                       \
            f16x8 bl3 = *(const f16x8*)&Wlo[48 + lr][kc];                      \
            acc0 = __builtin_amdgcn_mfma_f32_16x16x32_f16(ah, bh0, acc0, 0, 0, 0); \
            acc0 = __builtin_amdgcn_mfma_f32_16x16x32_f16(al, bh0, acc0, 0, 0, 0); \
            acc0 = __builtin_amdgcn_mfma_f32_16x16x32_f16(ah, bl0, acc0, 0, 0, 0); \
            acc1 = __builtin_amdgcn_mfma_f32_16x16x32_f16(ah, bh1, acc1, 0, 0, 0); \
            acc1 = __builtin_amdgcn_mfma_f32_16x16x32_f16(al, bh1, acc1, 0, 0, 0); \
            acc1 = __builtin_amdgcn_mfma_f32_16x16x32_f16(ah, bl1, acc1, 0, 0, 0); \
            acc2 = __builtin_amdgcn_mfma_f32_16x16x32_f16(ah, bh2, acc2, 0, 0, 0); \
            acc2 = __builtin_amdgcn_mfma_f32_16x16x32_f16(al, bh2, acc2, 0, 0, 0); \
            acc2 = __builtin_amdgcn_mfma_f32_16x16x32_f16(ah, bl2, acc2, 0, 0, 0); \
            acc3 = __builtin_amdgcn_mfma_f32_16x16x32_f16(ah, bh3, acc3, 0, 0, 0); \
            acc3 = __builtin_amdgcn_mfma_f32_16x16x32_f16(al, bh3, acc3, 0, 0, 0); \
            acc3 = __builtin_amdgcn_mfma_f32_16x16x32_f16(ah, bl3, acc3, 0, 0, 0); \
        }

        LOADP(0)
        LOADQ(64)
        for (int ch = 0; ch < 16; ch += 2) {
            // even chunk: write p -> LDS, refill p (ch+2), compute
            __syncthreads();
            WRITE_LDS(pa0, pa1, pa2, pa3, pw0, pw1)
            __syncthreads();
            if (ch + 2 < 16) { LOADP((ch + 2) * 64) }
            INNER_MFMA
            // odd chunk: write q -> LDS, refill q (ch+3), compute
            __syncthreads();
            WRITE_LDS(qa0, qa1, qa2, qa3, qw0, qw1)
            __syncthreads();
            if (ch + 3 < 16) { LOADQ((ch + 3) * 64) }
            INNER_MFMA
        }
#undef LOADP
#undef LOADQ
#undef WRITE_LDS
#undef INNER_MFMA
        __syncthreads();
        // D -> Sl (R16-verified C/D layout: row = lg*4 + r, col = lr)
#pragma unroll
        for (int r = 0; r < 4; ++r) {
            Sl[wv * 16 + lg * 4 + r][lr] = acc0[r] * INV_WSCALE;
            Sl[wv * 16 + lg * 4 + r][16 + lr] = acc1[r] * INV_WSCALE;
            Sl[wv * 16 + lg * 4 + r][32 + lr] = acc2[r] * INV_WSCALE;
            Sl[wv * 16 + lg * 4 + r][48 + lr] = acc3[r] * INV_WSCALE;
        }
        __syncthreads();
        if (tid < 128) {   // row phase: first-index argmax + exp-sum
            float m = Sl[tid][0];
            int am = 0;
#pragma unroll
            for (int c = 1; c < E; ++c) {
                float v = Sl[tid][c];
                if (v > m) { m = v; am = c; }
            }
            float ssum = 0.f;
#pragma unroll
            for (int c = 0; c < E; ++c) ssum += __expf(Sl[tid][c] - m);
            float inv = 1.0f / ssum;   // softmax value at the argmax
            gate[t0 + tid] = inv;
            idx[t0 + tid] = am;
            sm[tid] = m;
            sinv[tid] = inv;
        }
        __syncthreads();
        if (tid < E) {     // column phase: partial me sums (deterministic)
            float cs = 0.f;
#pragma unroll 8
            for (int r = 0; r < 128; ++r)
                cs += __expf(Sl[r][tid] - sm[r]) * sinv[r];
            me_part[bid * E + tid] = cs;
        }
    } else {
        int fb = bid - GEMM_BLOCKS;
        f32x4 z = {0.f, 0.f, 0.f, 0.f};
        f32x4* o4 = (f32x4*)out;
        for (unsigned i = (unsigned)fb * NTHR + tid; i < N4ALL;
             i += FILL_BLOCKS * NTHR)
            o4[i] = z;
    }
}

// ---------------- K2: ordered scan + scatter + counts + me-reduce + l_aux ----
// R8's proven kernel; me_part now spans 64 GEMM blocks.
__global__ __launch_bounds__(256) void k_scan(const int* __restrict__ idx,
                                              const float* __restrict__ gate,
                                              const float* __restrict__ me_part,
                                              float* __restrict__ out) {
    int e = blockIdx.x;
    int tid = threadIdx.x;
    int lane = tid & 63;
    int wid = tid >> 6;
    __shared__ int wsum[4];
    __shared__ float red[256];
    int running = 0;
    for (int ch = 0; ch < S / 256; ++ch) {
        int t = ch * 256 + tid;
        bool f = (idx[t] == e);
        unsigned long long b = __ballot(f);
        int pre = __popcll(b & ((1ull << lane) - 1ull));
        if (lane == 0) wsum[wid] = __popcll(b);
        __syncthreads();
        int off = running;
#pragma unroll
        for (int w2 = 0; w2 < 4; ++w2)
            if (w2 < wid) off += wsum[w2];
        int p = off + pre;
        if (f && p < CAP) {
            size_t o = 1 + (size_t)t * (E * CAP) + (size_t)e * CAP + (size_t)p;
            out[o] = gate[t];                 // combine_weights
            out[o + (size_t)SEC] = 1.0f;      // dispatch_mask
        }
        running += wsum[0] + wsum[1] + wsum[2] + wsum[3];
        __syncthreads();
    }
    // me reduction: me_sum[e] = sum over 64 GEMM blocks' partials
    red[tid] = (tid < GEMM_BLOCKS) ? me_part[tid * E + e] : 0.f;
    __syncthreads();
    for (int s2 = 128; s2 > 0; s2 >>= 1) {
        if (tid < s2) red[tid] += red[tid + s2];
        __syncthreads();
    }
    if (tid == 0) {
        out[1 + 2 * (size_t)SEC + e] = (float)running;   // exp_counts (pre-drop)
        float la = red[0] * (1.0f / (float)S) *
                   ((float)running / (float)S) * (float)E;
        atomicAdd(out, la);                              // l_aux
    }
}

extern "C" void kernel_launch(void* const* d_in, const int* in_sizes, int n_in,
                              void* d_out, int out_size, void* d_ws, size_t ws_size,
                              hipStream_t stream) {
    const float* x = (const float*)d_in[0];      // [S, Dm] fp32
    const float* w = (const float*)d_in[1];      // [E, Dm] fp32
    float* out = (float*)d_out;

    // ws layout
    float* me_part = (float*)d_ws;               // [64][64] = 16 KB
    float* gate = me_part + GEMM_BLOCKS * E;     // S floats
    int* idx = (int*)(gate + S);                 // S ints

    k_main<<<dim3(GEMM_BLOCKS + FILL_BLOCKS), dim3(NTHR), 0, stream>>>(
        x, w, gate, idx, me_part, out);
    k_scan<<<dim3(64), dim3(256), 0, stream>>>(idx, gate, me_part, out);
}

// Round 19
// 136.673 us; speedup vs baseline: 1.1003x; 1.0515x over previous
//
#include <hip/hip_runtime.h>
#include <cstdint>
#include <cstddef>

#define S 8192
#define Dm 1024
#define E 64
#define CAP 128
#define SEC 67108864ull   // S*E*CAP
// out layout (float32 elements), out_size = 1 + 2*SEC + 64 = 134,217,793:
//   [0] l_aux | [1,1+SEC) combine | [1+SEC,1+2SEC) dispatch | [1+2SEC,+64) counts
// K1 fill zeroes elements [0,134217792); leftover element = counts[63] is
// written unconditionally by k_scan.

#define GEMM_BLOCKS 256   // 32 tokens x 64 experts each
#define FILL_BLOCKS 1792  // grid 2048
#define N4ALL 33554448u
#define WSCALE 4096.0f    // keep w_hi/w_lo out of fp16-denorm range
#define INV_WSCALE (1.0f / 4096.0f)

typedef float f32x4 __attribute__((ext_vector_type(4)));
typedef _Float16 f16x8 __attribute__((ext_vector_type(8)));

// Raw barrier: LDS-ordering only (lgkmcnt(0)), does NOT drain vmcnt — global
// prefetch loads stay in flight across chunk barriers (the __syncthreads
// vmcnt(0) drain was clamping every prefetch scheme to ~1 chunk of distance).
// sched_barrier(0) pins ordering per guide rule #18.
#define RAWBAR                                                                 \
    asm volatile("s_waitcnt lgkmcnt(0)" ::: "memory");                         \
    __builtin_amdgcn_sched_barrier(0);                                         \
    __builtin_amdgcn_s_barrier();                                              \
    __builtin_amdgcn_sched_barrier(0);

// convert 8 fp32 (two float4) -> f16 hi + f16 lo, store as 16B each
#define CV8(H, L, ROW, COL, V0, V1, SCALE) do {                                \
    f16x8 hh, ll; float t_;                                                    \
    t_ = (V0).x * (SCALE); hh[0] = (_Float16)t_; ll[0] = (_Float16)(t_ - (float)hh[0]); \
    t_ = (V0).y * (SCALE); hh[1] = (_Float16)t_; ll[1] = (_Float16)(t_ - (float)hh[1]); \
    t_ = (V0).z * (SCALE); hh[2] = (_Float16)t_; ll[2] = (_Float16)(t_ - (float)hh[2]); \
    t_ = (V0).w * (SCALE); hh[3] = (_Float16)t_; ll[3] = (_Float16)(t_ - (float)hh[3]); \
    t_ = (V1).x * (SCALE); hh[4] = (_Float16)t_; ll[4] = (_Float16)(t_ - (float)hh[4]); \
    t_ = (V1).y * (SCALE); hh[5] = (_Float16)t_; ll[5] = (_Float16)(t_ - (float)hh[5]); \
    t_ = (V1).z * (SCALE); hh[6] = (_Float16)t_; ll[6] = (_Float16)(t_ - (float)hh[6]); \
    t_ = (V1).w * (SCALE); hh[7] = (_Float16)t_; ll[7] = (_Float16)(t_ - (float)hh[7]); \
    *(f16x8*)&H[ROW][COL] = hh;                                                \
    *(f16x8*)&L[ROW][COL] = ll;                                                \
} while (0)

// ---------------- K1: fused {MFMA-GEMM+softmax+argmax} + 537MB zero-fill -----
// R16 (verified fp16x3 MFMA) with ONE change: the chunk loop's two
// __syncthreads() replaced by RAWBAR (lgkmcnt-only). Global prefetch loads now
// truly span 2 chunks instead of being drained at every barrier.
__global__ __launch_bounds__(256) void k_main(const float* __restrict__ x,
                                              const float* __restrict__ w,
                                              float* __restrict__ gate,
                                              int* __restrict__ idx,
                                              float* __restrict__ me_part,
                                              float* __restrict__ out) {
    int bid = blockIdx.x;
    int tid = threadIdx.x;
    if (bid < GEMM_BLOCKS) {
        __shared__ _Float16 Ah[32][80];   // 5 KB   (row 160B: b128-aligned)
        __shared__ _Float16 Alo[32][80];  // 5 KB
        __shared__ _Float16 Wh[64][80];   // 10 KB
        __shared__ _Float16 Wlo[64][80];  // 10 KB
        __shared__ float Sl[32][66];      // 8.4 KB logits tile (epilogue)
        __shared__ float sm[32];
        __shared__ float sinv[32];
        int t0 = bid * 32;
        int sr = tid >> 3;             // staging row 0..31
        int sc = (tid & 7) * 8;        // staging col (halves/floats)
        const float* asrc = x + (size_t)(t0 + sr) * Dm + (tid & 7) * 8;
        const float* wsrc0 = w + (size_t)sr * Dm + (tid & 7) * 8;
        const float* wsrc1 = wsrc0 + 32 * (size_t)Dm;

        // MFMA work split: wave wv -> m-tile (wv&1), n-pair (wv>>1)
        int wv = tid >> 6;
        int l = tid & 63;
        int lr = l & 15;               // A row / B col within tile
        int lg = l >> 4;               // k-group 0..3
        int mt = wv & 1;               // m-tile 0/1 (16 tokens each)
        int np = wv >> 1;              // n-pair 0/1 (32 experts each)
        f32x4 acc0 = {0.f, 0.f, 0.f, 0.f};   // n-tile np*2
        f32x4 acc1 = {0.f, 0.f, 0.f, 0.f};   // n-tile np*2+1

        // 2-deep prefetch: p = even chunks, q = odd chunks
        float4 pa0 = *(const float4*)(asrc + 0);
        float4 pa1 = *(const float4*)(asrc + 4);
        float4 pw0 = *(const float4*)(wsrc0 + 0);
        float4 pw1 = *(const float4*)(wsrc0 + 4);
        float4 pw2 = *(const float4*)(wsrc1 + 0);
        float4 pw3 = *(const float4*)(wsrc1 + 4);
        float4 qa0 = *(const float4*)(asrc + 64);
        float4 qa1 = *(const float4*)(asrc + 68);
        float4 qw0 = *(const float4*)(wsrc0 + 64);
        float4 qw1 = *(const float4*)(wsrc0 + 68);
        float4 qw2 = *(const float4*)(wsrc1 + 64);
        float4 qw3 = *(const float4*)(wsrc1 + 68);

#define WRITE_LDS(A0, A1, W0, W1, W2, W3)                                      \
        CV8(Ah, Alo, sr, sc, A0, A1, 1.0f);                                    \
        CV8(Wh, Wlo, sr, sc, W0, W1, WSCALE);                                  \
        CV8(Wh, Wlo, (32 + sr), sc, W2, W3, WSCALE);

#define LOADP(KB)                                                              \
        pa0 = *(const float4*)(asrc + (KB));                                   \
        pa1 = *(const float4*)(asrc + (KB) + 4);                               \
        pw0 = *(const float4*)(wsrc0 + (KB));                                  \
        pw1 = *(const float4*)(wsrc0 + (KB) + 4);                              \
        pw2 = *(const float4*)(wsrc1 + (KB));                                  \
        pw3 = *(const float4*)(wsrc1 + (KB) + 4);

#define LOADQ(KB)                                                              \
        qa0 = *(const float4*)(asrc + (KB));                                   \
        qa1 = *(const float4*)(asrc + (KB) + 4);                               \
        qw0 = *(const float4*)(wsrc0 + (KB));                                  \
        qw1 = *(const float4*)(wsrc0 + (KB) + 4);                              \
        qw2 = *(const float4*)(wsrc1 + (KB));                                  \
        qw3 = *(const float4*)(wsrc1 + (KB) + 4);

#define INNER_MFMA                                                             \
        _Pragma("unroll")                                                      \
        for (int ks = 0; ks < 2; ++ks) {                                       \
            int kc = ks * 32 + lg * 8;                                         \
            f16x8 ah = *(const f16x8*)&Ah[mt * 16 + lr][kc];                   \
            f16x8 al = *(const f16x8*)&Alo[mt * 16 + lr][kc];                  \
            f16x8 bh0 = *(const f16x8*)&Wh[np * 32 + lr][kc];                  \
            f16x8 bl0 = *(const f16x8*)&Wlo[np * 32 + lr][kc];                 \
            f16x8 bh1 = *(const f16x8*)&Wh[np * 32 + 16 + lr][kc];             \
            f16x8 bl1 = *(const f16x8*)&Wlo[np * 32 + 16 + lr][kc];            \
            acc0 = __builtin_amdgcn_mfma_f32_16x16x32_f16(ah, bh0, acc0, 0, 0, 0); \
            acc0 = __builtin_amdgcn_mfma_f32_16x16x32_f16(al, bh0, acc0, 0, 0, 0); \
            acc0 = __builtin_amdgcn_mfma_f32_16x16x32_f16(ah, bl0, acc0, 0, 0, 0); \
            acc1 = __builtin_amdgcn_mfma_f32_16x16x32_f16(ah, bh1, acc1, 0, 0, 0); \
            acc1 = __builtin_amdgcn_mfma_f32_16x16x32_f16(al, bh1, acc1, 0, 0, 0); \
            acc1 = __builtin_amdgcn_mfma_f32_16x16x32_f16(ah, bl1, acc1, 0, 0, 0); \
        }

        for (int ch = 0; ch < 16; ch += 2) {
            // even chunk: (raw) barrier, write p -> LDS, (raw) barrier,
            // refill p for ch+2 (stays in flight across barriers), compute
            RAWBAR
            WRITE_LDS(pa0, pa1, pw0, pw1, pw2, pw3)
            RAWBAR
            if (ch + 2 < 16) { LOADP((ch + 2) * 64) }
            INNER_MFMA
            // odd chunk
            RAWBAR
            WRITE_LDS(qa0, qa1, qw0, qw1, qw2, qw3)
            RAWBAR
            if (ch + 3 < 16) { LOADQ((ch + 3) * 64) }
            INNER_MFMA
        }
#undef WRITE_LDS
#undef LOADP
#undef LOADQ
#undef INNER_MFMA
        __syncthreads();
        // ---- D -> Sl (verified C/D layout: row=(l>>4)*4+r, col=l&15) ----
#pragma unroll
        for (int r = 0; r < 4; ++r) {
            Sl[mt * 16 + lg * 4 + r][np * 32 + lr] = acc0[r] * INV_WSCALE;
            Sl[mt * 16 + lg * 4 + r][np * 32 + 16 + lr] = acc1[r] * INV_WSCALE;
        }
        __syncthreads();
        if (tid < 32) {   // row phase: first-index argmax + exp-sum
            float m = Sl[tid][0];
            int am = 0;
#pragma unroll
            for (int c = 1; c < E; ++c) {
                float v = Sl[tid][c];
                if (v > m) { m = v; am = c; }
            }
            float ssum = 0.f;
#pragma unroll
            for (int c = 0; c < E; ++c) ssum += __expf(Sl[tid][c] - m);
            float inv = 1.0f / ssum;   // softmax value at the argmax
            gate[t0 + tid] = inv;
            idx[t0 + tid] = am;
            sm[tid] = m;
            sinv[tid] = inv;
        }
        __syncthreads();
        if (tid < E) {    // column phase: partial me sums (deterministic)
            float cs = 0.f;
#pragma unroll 8
            for (int r = 0; r < 32; ++r)
                cs += __expf(Sl[r][tid] - sm[r]) * sinv[r];
            me_part[bid * E + tid] = cs;
        }
    } else {
        int fb = bid - GEMM_BLOCKS;
        f32x4 z = {0.f, 0.f, 0.f, 0.f};
        f32x4* o4 = (f32x4*)out;
        for (unsigned i = (unsigned)fb * 256u + tid; i < N4ALL;
             i += FILL_BLOCKS * 256u)
            o4[i] = z;
    }
}

// ---------------- K2: ordered scan + scatter + counts + me-reduce + l_aux ----
// R8's proven kernel, verbatim. 64 blocks (one per expert) x 256 threads.
__global__ __launch_bounds__(256) void k_scan(const int* __restrict__ idx,
                                              const float* __restrict__ gate,
                                              const float* __restrict__ me_part,
                                              float* __restrict__ out) {
    int e = blockIdx.x;
    int tid = threadIdx.x;
    int lane = tid & 63;
    int wid = tid >> 6;
    __shared__ int wsum[4];
    __shared__ float red[256];
    int running = 0;
    for (int ch = 0; ch < S / 256; ++ch) {
        int t = ch * 256 + tid;
        bool f = (idx[t] == e);
        unsigned long long b = __ballot(f);
        int pre = __popcll(b & ((1ull << lane) - 1ull));
        if (lane == 0) wsum[wid] = __popcll(b);
        __syncthreads();
        int off = running;
#pragma unroll
        for (int w2 = 0; w2 < 4; ++w2)
            if (w2 < wid) off += wsum[w2];
        int p = off + pre;
        if (f && p < CAP) {
            size_t o = 1 + (size_t)t * (E * CAP) + (size_t)e * CAP + (size_t)p;
            out[o] = gate[t];                 // combine_weights
            out[o + (size_t)SEC] = 1.0f;      // dispatch_mask
        }
        running += wsum[0] + wsum[1] + wsum[2] + wsum[3];
        __syncthreads();
    }
    // me reduction: me_sum[e] = sum over 256 blocks' partials
    red[tid] = me_part[tid * E + e];
    __syncthreads();
    for (int s2 = 128; s2 > 0; s2 >>= 1) {
        if (tid < s2) red[tid] += red[tid + s2];
        __syncthreads();
    }
    if (tid == 0) {
        out[1 + 2 * (size_t)SEC + e] = (float)running;   // exp_counts (pre-drop)
        float la = red[0] * (1.0f / (float)S) *
                   ((float)running / (float)S) * (float)E;
        atomicAdd(out, la);                              // l_aux
    }
}

extern "C" void kernel_launch(void* const* d_in, const int* in_sizes, int n_in,
                              void* d_out, int out_size, void* d_ws, size_t ws_size,
                              hipStream_t stream) {
    const float* x = (const float*)d_in[0];      // [S, Dm] fp32
    const float* w = (const float*)d_in[1];      // [E, Dm] fp32
    float* out = (float*)d_out;

    // ws layout
    float* me_part = (float*)d_ws;               // [256][64] = 64 KB
    float* gate = me_part + GEMM_BLOCKS * E;     // S floats
    int* idx = (int*)(gate + S);                 // S ints

    k_main<<<dim3(GEMM_BLOCKS + FILL_BLOCKS), dim3(256), 0, stream>>>(
        x, w, gate, idx, me_part, out);
    k_scan<<<dim3(64), dim3(256), 0, stream>>>(idx, gate, me_part, out);
}

// Round 20
// 130.586 us; speedup vs baseline: 1.1516x; 1.0466x over previous
//
#include <hip/hip_runtime.h>
#include <cstdint>
#include <cstddef>

#define S 8192
#define Dm 1024
#define E 64
#define CAP 128
#define SEC 67108864ull   // S*E*CAP
// out layout (float32 elements), out_size = 1 + 2*SEC + 64 = 134,217,793:
//   [0] l_aux | [1,1+SEC) combine | [1+SEC,1+2SEC) dispatch | [1+2SEC,+64) counts
// K1 fill zeroes elements [0,134217792); leftover element = counts[63] is
// written unconditionally by k_scan (every (e,q=3) block writes counts[e]).

#define GEMM_BLOCKS 256   // 32 tokens x 64 experts each (R14 champion GEMM)
#define FILL_BLOCKS 1792  // grid 2048
#define N4ALL 33554448u   // float4 chunks covering elements [0, 134217792)
#define CHUNK4 18725u     // ceil(N4ALL / FILL_BLOCKS): per-block contiguous run

typedef float f32x4 __attribute__((ext_vector_type(4)));

// ---------------- K1: fused {GEMM+softmax+argmax} + 537MB zero-fill ----------
// R14 champion GEMM (VALU 2tok x 4exp, 2-deep p/q prefetch). Changes:
//  (a) fill branch is BLOCK-CHUNKED: each fill block streams a contiguous
//      ~293KB region (4KB contiguous per iteration) instead of 16B-granular
//      grid-stride — longer write bursts, fewer HBM read/write turnarounds
//      against the GEMM's staging loads (the R19-diagnosed mixed-traffic wall).
//  (b) epilogue additionally emits exact per-block expert counts (cnt_g),
//      enabling the 4x-parallel k_scan.
__global__ __launch_bounds__(256) void k_main(const float* __restrict__ x,
                                              const float* __restrict__ w,
                                              float* __restrict__ gate,
                                              int* __restrict__ idx,
                                              float* __restrict__ me_part,
                                              int* __restrict__ cnt_g,
                                              float* __restrict__ out) {
    int bid = blockIdx.x;
    int tid = threadIdx.x;
    if (bid < GEMM_BLOCKS) {
        __shared__ float Al[32][68];   // 272B rows: 16B-aligned (b128 reads)
        __shared__ float Wl[64][68];
        __shared__ float sm[32];
        __shared__ float sinv[32];
        __shared__ int sidx[32];
        int rt = (tid & 15) * 2;       // token pair base
        int ce = (tid >> 4) * 4;       // expert quad base
        int t0 = bid * 32;
        const float* asrc = x + (size_t)(t0 + (tid >> 3)) * Dm + (tid & 7) * 8;
        const float* wsrc0 = w + (size_t)(tid >> 3) * Dm + (tid & 7) * 8;
        const float* wsrc1 = wsrc0 + 32 * (size_t)Dm;
        float* adst = &Al[tid >> 3][(tid & 7) * 8];
        float* wdst0 = &Wl[tid >> 3][(tid & 7) * 8];
        float* wdst1 = &Wl[32 + (tid >> 3)][(tid & 7) * 8];

        float4 acc0 = make_float4(0.f, 0.f, 0.f, 0.f);  // tok rt,   exp ce..+3
        float4 acc1 = make_float4(0.f, 0.f, 0.f, 0.f);  // tok rt+1, exp ce..+3

        // 2-deep prefetch: set p = even chunks, set q = odd chunks
        float4 pa0 = *(const float4*)(asrc + 0);
        float4 pa1 = *(const float4*)(asrc + 4);
        float4 pw0 = *(const float4*)(wsrc0 + 0);
        float4 pw1 = *(const float4*)(wsrc0 + 4);
        float4 pw2 = *(const float4*)(wsrc1 + 0);
        float4 pw3 = *(const float4*)(wsrc1 + 4);
        float4 qa0 = *(const float4*)(asrc + 64);
        float4 qa1 = *(const float4*)(asrc + 68);
        float4 qw0 = *(const float4*)(wsrc0 + 64);
        float4 qw1 = *(const float4*)(wsrc0 + 68);
        float4 qw2 = *(const float4*)(wsrc1 + 64);
        float4 qw3 = *(const float4*)(wsrc1 + 68);

#define INNER_COMPUTE                                                          \
        _Pragma("unroll 4")                                                    \
        for (int k4 = 0; k4 < 16; ++k4) {                                      \
            float4 a0 = *(const float4*)&Al[rt][k4 * 4];                       \
            float4 a1 = *(const float4*)&Al[rt + 1][k4 * 4];                   \
            float4 w0 = *(const float4*)&Wl[ce + 0][k4 * 4];                   \
            float4 w1 = *(const float4*)&Wl[ce + 1][k4 * 4];                   \
            float4 w2 = *(const float4*)&Wl[ce + 2][k4 * 4];                   \
            float4 w3 = *(const float4*)&Wl[ce + 3][k4 * 4];                   \
            acc0.x = fmaf(a0.w, w0.w, fmaf(a0.z, w0.z, fmaf(a0.y, w0.y, fmaf(a0.x, w0.x, acc0.x)))); \
            acc0.y = fmaf(a0.w, w1.w, fmaf(a0.z, w1.z, fmaf(a0.y, w1.y, fmaf(a0.x, w1.x, acc0.y)))); \
            acc0.z = fmaf(a0.w, w2.w, fmaf(a0.z, w2.z, fmaf(a0.y, w2.y, fmaf(a0.x, w2.x, acc0.z)))); \
            acc0.w = fmaf(a0.w, w3.w, fmaf(a0.z, w3.z, fmaf(a0.y, w3.y, fmaf(a0.x, w3.x, acc0.w)))); \
            acc1.x = fmaf(a1.w, w0.w, fmaf(a1.z, w0.z, fmaf(a1.y, w0.y, fmaf(a1.x, w0.x, acc1.x)))); \
            acc1.y = fmaf(a1.w, w1.w, fmaf(a1.z, w1.z, fmaf(a1.y, w1.y, fmaf(a1.x, w1.x, acc1.y)))); \
            acc1.z = fmaf(a1.w, w2.w, fmaf(a1.z, w2.z, fmaf(a1.y, w2.y, fmaf(a1.x, w2.x, acc1.z)))); \
            acc1.w = fmaf(a1.w, w3.w, fmaf(a1.z, w3.z, fmaf(a1.y, w3.y, fmaf(a1.x, w3.x, acc1.w)))); \
        }

        for (int ch = 0; ch < 16; ch += 2) {
            // even chunk: regs(p) -> LDS, refill p for ch+2, compute
            __syncthreads();
            *(float4*)(adst + 0) = pa0;  *(float4*)(adst + 4) = pa1;
            *(float4*)(wdst0 + 0) = pw0; *(float4*)(wdst0 + 4) = pw1;
            *(float4*)(wdst1 + 0) = pw2; *(float4*)(wdst1 + 4) = pw3;
            __syncthreads();
            if (ch + 2 < 16) {
                int kb = (ch + 2) * 64;
                pa0 = *(const float4*)(asrc + kb);
                pa1 = *(const float4*)(asrc + kb + 4);
                pw0 = *(const float4*)(wsrc0 + kb);
                pw1 = *(const float4*)(wsrc0 + kb + 4);
                pw2 = *(const float4*)(wsrc1 + kb);
                pw3 = *(const float4*)(wsrc1 + kb + 4);
            }
            INNER_COMPUTE
            // odd chunk: regs(q) -> LDS, refill q for ch+3, compute
            __syncthreads();
            *(float4*)(adst + 0) = qa0;  *(float4*)(adst + 4) = qa1;
            *(float4*)(wdst0 + 0) = qw0; *(float4*)(wdst0 + 4) = qw1;
            *(float4*)(wdst1 + 0) = qw2; *(float4*)(wdst1 + 4) = qw3;
            __syncthreads();
            if (ch + 3 < 16) {
                int kb = (ch + 3) * 64;
                qa0 = *(const float4*)(asrc + kb);
                qa1 = *(const float4*)(asrc + kb + 4);
                qw0 = *(const float4*)(wsrc0 + kb);
                qw1 = *(const float4*)(wsrc0 + kb + 4);
                qw2 = *(const float4*)(wsrc1 + kb);
                qw3 = *(const float4*)(wsrc1 + kb + 4);
            }
            INNER_COMPUTE
        }
#undef INNER_COMPUTE
        __syncthreads();
        // ---- epilogue: logits tile -> LDS (reuse Al), softmax/argmax ----
        Al[rt][ce + 0] = acc0.x; Al[rt][ce + 1] = acc0.y;
        Al[rt][ce + 2] = acc0.z; Al[rt][ce + 3] = acc0.w;
        Al[rt + 1][ce + 0] = acc1.x; Al[rt + 1][ce + 1] = acc1.y;
        Al[rt + 1][ce + 2] = acc1.z; Al[rt + 1][ce + 3] = acc1.w;
        __syncthreads();
        if (tid < 32) {   // row phase: first-index argmax + exp-sum
            float m = Al[tid][0];
            int am = 0;
#pragma unroll
            for (int c = 1; c < E; ++c) {
                float v = Al[tid][c];
                if (v > m) { m = v; am = c; }
            }
            float ssum = 0.f;
#pragma unroll
            for (int c = 0; c < E; ++c) ssum += __expf(Al[tid][c] - m);
            float inv = 1.0f / ssum;   // softmax value at the argmax
            gate[t0 + tid] = inv;
            idx[t0 + tid] = am;
            sm[tid] = m;
            sinv[tid] = inv;
            sidx[tid] = am;
        }
        __syncthreads();
        if (tid < E) {    // column phase: me partials + exact expert histogram
            float cs = 0.f;
            int cnt = 0;
#pragma unroll 8
            for (int r = 0; r < 32; ++r) {
                cs += __expf(Al[r][tid] - sm[r]) * sinv[r];
                cnt += (sidx[r] == tid) ? 1 : 0;
            }
            me_part[bid * E + tid] = cs;
            cnt_g[bid * E + tid] = cnt;
        }
    } else {
        // block-chunked fill: block owns chunks [base4, base4+CHUNK4), i.e. a
        // contiguous ~293KB region; each iteration writes 4KB contiguous.
        unsigned base4 = (unsigned)(bid - GEMM_BLOCKS) * CHUNK4;
        f32x4 z = {0.f, 0.f, 0.f, 0.f};
        f32x4* o4 = (f32x4*)out;
        for (unsigned j = tid; j < CHUNK4; j += 256u) {
            unsigned i = base4 + j;
            if (i < N4ALL) o4[i] = z;
        }
    }
}

// ---------------- K2: quartered scan + scatter + counts + me-reduce + l_aux --
// 256 blocks x 256 threads: block (e = bid>>2, q = bid&3) scans tokens
// [2048q, 2048q+2048) for expert e, seeded with base = sum of cnt_g over GEMM
// blocks [0, 64q) — exact, so quarters are independent. 8 ballot iterations
// (proven R8 core) instead of 32; 4x the parallelism of the old k_scan.
__global__ __launch_bounds__(256) void k_scan(const int* __restrict__ idx,
                                              const float* __restrict__ gate,
                                              const float* __restrict__ me_part,
                                              const int* __restrict__ cnt_g,
                                              float* __restrict__ out) {
    int e = blockIdx.x >> 2;
    int q = blockIdx.x & 3;
    int tid = threadIdx.x;
    int lane = tid & 63;
    int wid = tid >> 6;
    __shared__ int wsum[4];
    __shared__ int ired[256];
    __shared__ float red[256];
    // base = tokens of expert e in [0, 2048q)
    int nb = q << 6;                   // GEMM blocks before this quarter
    int a = 0;
    for (int b = tid; b < nb; b += 256) a += cnt_g[b * E + e];
    ired[tid] = a;
    __syncthreads();
    for (int s2 = 128; s2 > 0; s2 >>= 1) {
        if (tid < s2) ired[tid] += ired[tid + s2];
        __syncthreads();
    }
    int running = ired[0];
    __syncthreads();
    for (int ch = 0; ch < 8; ++ch) {
        int t = q * 2048 + ch * 256 + tid;
        bool f = (idx[t] == e);
        unsigned long long b = __ballot(f);
        int pre = __popcll(b & ((1ull << lane) - 1ull));
        if (lane == 0) wsum[wid] = __popcll(b);
        __syncthreads();
        int off = running;
#pragma unroll
        for (int w2 = 0; w2 < 4; ++w2)
            if (w2 < wid) off += wsum[w2];
        int p = off + pre;             // global position-in-expert (pre-drop)
        if (f && p < CAP) {
            size_t o = 1 + (size_t)t * (E * CAP) + (size_t)e * CAP + (size_t)p;
            out[o] = gate[t];                 // combine_weights
            out[o + (size_t)SEC] = 1.0f;      // dispatch_mask
        }
        running += wsum[0] + wsum[1] + wsum[2] + wsum[3];
        __syncthreads();
    }
    if (q == 3) {   // this block's running = full pre-drop count for e
        red[tid] = me_part[tid * E + e];
        __syncthreads();
        for (int s2 = 128; s2 > 0; s2 >>= 1) {
            if (tid < s2) red[tid] += red[tid + s2];
            __syncthreads();
        }
        if (tid == 0) {
            out[1 + 2 * (size_t)SEC + e] = (float)running;   // exp_counts
            float la = red[0] * (1.0f / (float)S) *
                       ((float)running / (float)S) * (float)E;
            atomicAdd(out, la);                              // l_aux
        }
    }
}

extern "C" void kernel_launch(void* const* d_in, const int* in_sizes, int n_in,
                              void* d_out, int out_size, void* d_ws, size_t ws_size,
                              hipStream_t stream) {
    const float* x = (const float*)d_in[0];      // [S, Dm] fp32
    const float* w = (const float*)d_in[1];      // [E, Dm] fp32
    float* out = (float*)d_out;

    // ws layout
    float* me_part = (float*)d_ws;               // [256][64] = 64 KB
    float* gate = me_part + GEMM_BLOCKS * E;     // S floats
    int* idx = (int*)(gate + S);                 // S ints
    int* cnt_g = idx + S;                        // [256][64] = 64 KB

    k_main<<<dim3(GEMM_BLOCKS + FILL_BLOCKS), dim3(256), 0, stream>>>(
        x, w, gate, idx, me_part, cnt_g, out);
    k_scan<<<dim3(256), dim3(256), 0, stream>>>(idx, gate, me_part, cnt_g, out);
}

// Round 21
// 128.994 us; speedup vs baseline: 1.1658x; 1.0123x over previous
//
#include <hip/hip_runtime.h>
#include <cstdint>
#include <cstddef>

#define S 8192
#define Dm 1024
#define E 64
#define CAP 128
#define SEC 67108864ull   // S*E*CAP
// out layout (float32 elements), out_size = 1 + 2*SEC + 64 = 134,217,793:
//   [0] l_aux | [1,1+SEC) combine | [1+SEC,1+2SEC) dispatch | [1+2SEC,+64) counts
// Coverage map (every element written every call):
//   K1 fill: elements [1+SEC+3, 134217792) zeroed via chunks [16777217,33554448)
//            + scalar zeros at out[1+SEC],out[2+SEC],out[3+SEC]; la_ws zeroed
//   K2: counts[0..63] written unconditionally (incl. element 134217792)
//   K3: combine elements [1, 1+SEC) = final values; dispatch 1.0s; out[0]=l_aux

#define GEMM_BLOCKS 256   // 32 tokens x 64 experts (R17-verified MFMA GEMM)
#define FILL_BLOCKS 1792
#define B0 16777217u      // first aligned chunk of the dispatch-half fill
#define TCH 16777231u     // total chunks to fill
#define CH 9363u          // ceil(TCH / FILL_BLOCKS)
#define N4END 33554448u
#define WSCALE 4096.0f
#define INV_WSCALE (1.0f / 4096.0f)

typedef float f32x4 __attribute__((ext_vector_type(4)));
typedef _Float16 f16x4 __attribute__((ext_vector_type(4)));
typedef _Float16 f16x8 __attribute__((ext_vector_type(8)));

#define CV4(H, L, ROW, COL, V, SCALE) do {                                     \
    f16x4 hh, ll; float t_;                                                    \
    t_ = (V).x * (SCALE); hh[0] = (_Float16)t_; ll[0] = (_Float16)(t_ - (float)hh[0]); \
    t_ = (V).y * (SCALE); hh[1] = (_Float16)t_; ll[1] = (_Float16)(t_ - (float)hh[1]); \
    t_ = (V).z * (SCALE); hh[2] = (_Float16)t_; ll[2] = (_Float16)(t_ - (float)hh[2]); \
    t_ = (V).w * (SCALE); hh[3] = (_Float16)t_; ll[3] = (_Float16)(t_ - (float)hh[3]); \
    *(f16x4*)&H[ROW][COL] = hh;                                                \
    *(f16x4*)&L[ROW][COL] = ll;                                                \
} while (0)

// ---------------- K1: MFMA GEMM+softmax (R17-verified) + dispatch-half fill --
__global__ __launch_bounds__(512) void k_main(const float* __restrict__ x,
                                              const float* __restrict__ w,
                                              float* __restrict__ gate,
                                              int* __restrict__ idx,
                                              float* __restrict__ me_part,
                                              int* __restrict__ cnt_g,
                                              float* __restrict__ la_ws,
                                              float* __restrict__ out) {
    int bid = blockIdx.x;
    int tid = threadIdx.x;
    if (bid < GEMM_BLOCKS) {
        __shared__ _Float16 Ah[32][72];
        __shared__ _Float16 Alo[32][72];
        __shared__ _Float16 Wh[64][72];
        __shared__ _Float16 Wlo[64][72];
        __shared__ float Sl[32][66];
        __shared__ float sm[32];
        __shared__ float sinv[32];
        __shared__ int sidx[32];
        int t0 = bid * 32;
        int ar = tid >> 4;                 // 0..31
        int ac = (tid & 15) * 4;
        int wr = tid >> 3;                 // 0..63
        int wc = (tid & 7) * 8;
        const float* asrc = x + (size_t)(t0 + ar) * Dm + ac;
        const float* wsrc = w + (size_t)wr * Dm + wc;

        int wv = tid >> 6;
        int l = tid & 63;
        int lr = l & 15;
        int lg = l >> 4;
        int mt = wv & 1;
        int nt = wv >> 1;
        f32x4 acc = {0.f, 0.f, 0.f, 0.f};

        float4 pa = *(const float4*)(asrc + 0);
        float4 pw0 = *(const float4*)(wsrc + 0);
        float4 pw1 = *(const float4*)(wsrc + 4);
        float4 qa = *(const float4*)(asrc + 64);
        float4 qw0 = *(const float4*)(wsrc + 64);
        float4 qw1 = *(const float4*)(wsrc + 68);

#define WRITE_LDS(A, W0, W1)                                                   \
        CV4(Ah, Alo, ar, ac, A, 1.0f);                                         \
        CV4(Wh, Wlo, wr, wc, W0, WSCALE);                                      \
        CV4(Wh, Wlo, wr, (wc + 4), W1, WSCALE);
#define LOADP(KB)                                                              \
        pa = *(const float4*)(asrc + (KB));                                    \
        pw0 = *(const float4*)(wsrc + (KB));                                   \
        pw1 = *(const float4*)(wsrc + (KB) + 4);
#define LOADQ(KB)                                                              \
        qa = *(const float4*)(asrc + (KB));                                    \
        qw0 = *(const float4*)(wsrc + (KB));                                   \
        qw1 = *(const float4*)(wsrc + (KB) + 4);
#define INNER_MFMA                                                             \
        _Pragma("unroll")                                                      \
        for (int ks = 0; ks < 2; ++ks) {                                       \
            int kc = ks * 32 + lg * 8;                                         \
            f16x8 ah = *(const f16x8*)&Ah[mt * 16 + lr][kc];                   \
            f16x8 al = *(const f16x8*)&Alo[mt * 16 + lr][kc];                  \
            f16x8 bh = *(const f16x8*)&Wh[nt * 16 + lr][kc];                   \
            f16x8 bl = *(const f16x8*)&Wlo[nt * 16 + lr][kc];                  \
            acc = __builtin_amdgcn_mfma_f32_16x16x32_f16(ah, bh, acc, 0, 0, 0); \
            acc = __builtin_amdgcn_mfma_f32_16x16x32_f16(al, bh, acc, 0, 0, 0); \
            acc = __builtin_amdgcn_mfma_f32_16x16x32_f16(ah, bl, acc, 0, 0, 0); \
        }

        for (int ch = 0; ch < 16; ch += 2) {
            __syncthreads();
            WRITE_LDS(pa, pw0, pw1)
            __syncthreads();
            if (ch + 2 < 16) { LOADP((ch + 2) * 64) }
            INNER_MFMA
            __syncthreads();
            WRITE_LDS(qa, qw0, qw1)
            __syncthreads();
            if (ch + 3 < 16) { LOADQ((ch + 3) * 64) }
            INNER_MFMA
        }
#undef WRITE_LDS
#undef LOADP
#undef LOADQ
#undef INNER_MFMA
        __syncthreads();
        // D -> Sl (R16/R17-verified C/D layout: row = lg*4 + r, col = lr)
#pragma unroll
        for (int r = 0; r < 4; ++r)
            Sl[mt * 16 + lg * 4 + r][nt * 16 + lr] = acc[r] * INV_WSCALE;
        __syncthreads();
        if (tid < 32) {   // row phase: first-index argmax + exp-sum
            float m = Sl[tid][0];
            int am = 0;
#pragma unroll
            for (int c = 1; c < E; ++c) {
                float v = Sl[tid][c];
                if (v > m) { m = v; am = c; }
            }
            float ssum = 0.f;
#pragma unroll
            for (int c = 0; c < E; ++c) ssum += __expf(Sl[tid][c] - m);
            float inv = 1.0f / ssum;
            gate[t0 + tid] = inv;
            idx[t0 + tid] = am;
            sm[tid] = m;
            sinv[tid] = inv;
            sidx[tid] = am;
        }
        __syncthreads();
        if (tid < E) {    // column phase: me partials + exact expert histogram
            float cs = 0.f;
            int cnt = 0;
#pragma unroll 8
            for (int r = 0; r < 32; ++r) {
                cs += __expf(Sl[r][tid] - sm[r]) * sinv[r];
                cnt += (sidx[r] == tid) ? 1 : 0;
            }
            me_part[bid * E + tid] = cs;
            cnt_g[bid * E + tid] = cnt;
        }
    } else {
        // block-chunked zero-fill of dispatch half + counts[0..62]
        int fb = bid - GEMM_BLOCKS;
        if (fb == 0 && tid == 0) {
            out[1 + SEC] = 0.f; out[2 + SEC] = 0.f; out[3 + SEC] = 0.f;
            la_ws[0] = 0.f;
        }
        unsigned base = B0 + (unsigned)fb * CH;
        f32x4 z = {0.f, 0.f, 0.f, 0.f};
        f32x4* o4 = (f32x4*)out;
        for (unsigned j = tid; j < CH; j += 512u) {
            unsigned i = base + j;
            if (i < N4END) o4[i] = z;
        }
    }
}

// ---------------- K2: quartered scan -> tg[], counts, l_aux accum ------------
// R20's proven quartered ballot scan; writes tg[t] = {local slot or -1, gate}
// for EVERY token instead of scattering into out (combine isn't zeroed yet).
__global__ __launch_bounds__(256) void k_scan(const int* __restrict__ idx,
                                              const float* __restrict__ gate,
                                              const float* __restrict__ me_part,
                                              const int* __restrict__ cnt_g,
                                              float2* __restrict__ tg,
                                              float* __restrict__ la_ws,
                                              float* __restrict__ out) {
    int e = blockIdx.x >> 2;
    int q = blockIdx.x & 3;
    int tid = threadIdx.x;
    int lane = tid & 63;
    int wid = tid >> 6;
    __shared__ int wsum[4];
    __shared__ int ired[256];
    __shared__ float red[256];
    int nb = q << 6;
    int a = 0;
    for (int b = tid; b < nb; b += 256) a += cnt_g[b * E + e];
    ired[tid] = a;
    __syncthreads();
    for (int s2 = 128; s2 > 0; s2 >>= 1) {
        if (tid < s2) ired[tid] += ired[tid + s2];
        __syncthreads();
    }
    int running = ired[0];
    __syncthreads();
    for (int ch = 0; ch < 8; ++ch) {
        int t = q * 2048 + ch * 256 + tid;
        bool f = (idx[t] == e);
        unsigned long long b = __ballot(f);
        int pre = __popcll(b & ((1ull << lane) - 1ull));
        if (lane == 0) wsum[wid] = __popcll(b);
        __syncthreads();
        int off = running;
#pragma unroll
        for (int w2 = 0; w2 < 4; ++w2)
            if (w2 < wid) off += wsum[w2];
        int p = off + pre;
        if (f) {   // every token written exactly once (by its argmax expert)
            int tgt = (p < CAP) ? e * CAP + p : -1;
            tg[t] = make_float2(__int_as_float(tgt), gate[t]);
        }
        running += wsum[0] + wsum[1] + wsum[2] + wsum[3];
        __syncthreads();
    }
    if (q == 3) {
        red[tid] = me_part[tid * E + e];
        __syncthreads();
        for (int s2 = 128; s2 > 0; s2 >>= 1) {
            if (tid < s2) red[tid] += red[tid + s2];
            __syncthreads();
        }
        if (tid == 0) {
            out[1 + 2 * (size_t)SEC + e] = (float)running;   // exp_counts
            float la = red[0] * (1.0f / (float)S) *
                       ((float)running / (float)S) * (float)E;
            atomicAdd(la_ws, la);
        }
    }
}

// ---------------- K3: merge-fill combine half + dispatch ones + l_aux --------
// Pure-write kernel: 2048 blocks x 256 thr, 4 tokens/block. Per token t the
// combine span out[1+8192t .. +8192) is written DIRECTLY with final values
// (zeros except slot tgt = gate): 2047 aligned float4 (4 cmp + 4 cndmask each;
// no dynamic vector index, rule #20) + 4 boundary scalars. Runs at fill BW —
// no concurrent reads to interfere (the R19/R20-diagnosed wall).
__global__ __launch_bounds__(256) void k_merge(const float2* __restrict__ tg,
                                               const float* __restrict__ la_ws,
                                               float* __restrict__ out) {
    int bid = blockIdx.x;
    int tid = threadIdx.x;
    if (bid == 0 && tid == 0) out[0] = la_ws[0];   // l_aux (K2 complete)
    f32x4* o4 = (f32x4*)out;
#pragma unroll
    for (int k = 0; k < 4; ++k) {
        int t = bid * 4 + k;
        float2 g = tg[t];
        int tgt = __float_as_int(g.x);     // local slot in [0,8192) or -1
        float gv = g.y;
        // aligned chunks j in [1,2048): global chunk 2048t+j covers local
        // combine indices [4j-1, 4j+3)
        for (int j = 1 + tid; j < 2048; j += 256) {
            int base = 4 * j - 1;
            f32x4 v;
            v[0] = (tgt == base) ? gv : 0.f;
            v[1] = (tgt == base + 1) ? gv : 0.f;
            v[2] = (tgt == base + 2) ? gv : 0.f;
            v[3] = (tgt == base + 3) ? gv : 0.f;
            o4[2048u * (unsigned)t + (unsigned)j] = v;
        }
        if (tid < 4) {   // boundary scalars: local c = 0,1,2,8191
            int c = (tid < 3) ? tid : 8191;
            out[1 + (size_t)t * 8192 + c] = (tgt == c) ? gv : 0.f;
        }
        if (tid == 4 && tgt >= 0)   // dispatch one (half zeroed by K1)
            out[1 + SEC + (size_t)t * 8192 + tgt] = 1.0f;
    }
}

extern "C" void kernel_launch(void* const* d_in, const int* in_sizes, int n_in,
                              void* d_out, int out_size, void* d_ws, size_t ws_size,
                              hipStream_t stream) {
    const float* x = (const float*)d_in[0];      // [S, Dm] fp32
    const float* w = (const float*)d_in[1];      // [E, Dm] fp32
    float* out = (float*)d_out;

    // ws layout
    float* me_part = (float*)d_ws;               // [256][64] = 64 KB
    float* gate = me_part + GEMM_BLOCKS * E;     // S floats
    int* idx = (int*)(gate + S);                 // S ints
    int* cnt_g = idx + S;                        // [256][64] = 64 KB
    float2* tg = (float2*)(cnt_g + GEMM_BLOCKS * E);   // S float2 = 64 KB
    float* la_ws = (float*)(tg + S);             // 1 float

    k_main<<<dim3(GEMM_BLOCKS + FILL_BLOCKS), dim3(512), 0, stream>>>(
        x, w, gate, idx, me_part, cnt_g, la_ws, out);
    k_scan<<<dim3(256), dim3(256), 0, stream>>>(
        idx, gate, me_part, cnt_g, tg, la_ws, out);
    k_merge<<<dim3(2048), dim3(256), 0, stream>>>(tg, la_ws, out);
}